// Round 9
// baseline (805.358 us; speedup 1.0000x reference)
//
#include <hip/hip_runtime.h>
#include <hip/hip_bf16.h>
#include <cstdint>
#include <cstddef>

// ---------------- types ----------------
typedef __bf16 bf16x8 __attribute__((ext_vector_type(8)));
typedef __bf16 bf16x4 __attribute__((ext_vector_type(4)));
typedef float  f32x4  __attribute__((ext_vector_type(4)));

#define D_MODEL 2048
#define SEQ     4096
#define BATCH   4
#define M_TOK   (BATCH * SEQ)            // 16384 tokens
#define ATTN_SCALE 0.08838834764831845f  // 128^-0.5

// ---- 256x256 GEMM geometry ----
#define BM 256
#define BN 256
#define BK 64
#define NT (D_MODEL / BK)                // 32 K-tiles
#define BUF_BYTES 65536                  // per buffer: A 32KB + B 32KB
#define B_OFF     32768                  // B region offset within buffer

#define NSEG   64
#define SEGLEN (SEQ / NSEG)              // 64

// ---------------- helpers ----------------
__device__ __forceinline__ void async_load16(const void* g, void* l) {
    __builtin_amdgcn_global_load_lds(
        (const __attribute__((address_space(1))) unsigned int*)g,
        (__attribute__((address_space(3))) unsigned int*)l,
        16, 0, 0);
}

__device__ __forceinline__ void wg_barrier() {
    __builtin_amdgcn_sched_barrier(0);
    __builtin_amdgcn_s_barrier();
    __builtin_amdgcn_sched_barrier(0);
}

#define VMCNT(n) asm volatile("s_waitcnt vmcnt(" #n ")" ::: "memory")

// ---------------- cast fp32 -> bf16 (8 elems / thread) ----------------
__global__ __launch_bounds__(256) void k_cast_bf16(const float* __restrict__ in,
                                                   __bf16* __restrict__ out,
                                                   int n8) {
    int i = blockIdx.x * 256 + threadIdx.x;
    if (i >= n8) return;
    const float4* in4 = (const float4*)in;
    float4 a = in4[2 * i];
    float4 b = in4[2 * i + 1];
    bf16x8 o;
    o[0] = (__bf16)a.x; o[1] = (__bf16)a.y; o[2] = (__bf16)a.z; o[3] = (__bf16)a.w;
    o[4] = (__bf16)b.x; o[5] = (__bf16)b.y; o[6] = (__bf16)b.z; o[7] = (__bf16)b.w;
    ((bf16x8*)out)[i] = o;
}

__global__ __launch_bounds__(256) void k_cast_w4(const float* __restrict__ w0,
                                                 const float* __restrict__ w1,
                                                 const float* __restrict__ w2,
                                                 const float* __restrict__ w3,
                                                 __bf16* __restrict__ out, int n8) {
    const float* srcs[4] = {w0, w1, w2, w3};
    const float* in = srcs[blockIdx.y];
    __bf16* o = out + (size_t)blockIdx.y * (size_t)n8 * 8;
    int i = blockIdx.x * 256 + threadIdx.x;
    if (i >= n8) return;
    const float4* in4 = (const float4*)in;
    float4 a = in4[2 * i];
    float4 b = in4[2 * i + 1];
    bf16x8 v;
    v[0] = (__bf16)a.x; v[1] = (__bf16)a.y; v[2] = (__bf16)a.z; v[3] = (__bf16)a.w;
    v[4] = (__bf16)b.x; v[5] = (__bf16)b.y; v[6] = (__bf16)b.z; v[7] = (__bf16)b.w;
    ((bf16x8*)o)[i] = v;
}

// ---------------- 256x256 GEMM: C = A (MxK) * B^T (B is NxK) ----------------
// 512 threads = 8 waves (2M x 4N), wave tile 128x64, MFMA 16x16x32 bf16.
// LDS: 2 buffers x (A[256][64] + B[256][64]) bf16 = 128 KiB, double buffered.
// Swizzle: 16B chunk c of row r at physical chunk c^(r&7); applied on the GLOBAL
// source of global_load_lds (LDS dest lane-linear) and on the ds_read side.
//
// Round-8 PMC showed LDS-read drain (2300 cyc/CU/K-tile) SERIAL with MFMA
// (2484 cyc): first MFMA consumed bf[0] = 9th of 12 reads -> waitcnt pass
// near-fully serialized each slice. This version software-pipelines within
// the wave, register-neutrally:
//   - read order: bf0[0..3], af[0..7], bf1[0..3]  (first MFMA waits on 5th read)
//   - slice-1 A fragments re-read into the SAME afr[i] slot right after the
//     4 slice-0 MFMAs that consume it (WAR reuse pins the read under the
//     MFMA stream; all 8 s1 A-reads in flight before slice-1 MFMAs start)
// MFMA becomes one contiguous 64-MFMA stream with reads hidden beneath it.
template <int PHI, typename OUT_T>
__device__ __forceinline__ void gemm256(const __bf16* __restrict__ A,
                                        const __bf16* __restrict__ Bm,
                                        const float* __restrict__ bias,
                                        OUT_T* __restrict__ C,
                                        int bx, int by) {
    extern __shared__ bf16x8 lds_dyn[];
    char* lds = (char*)lds_dyn;

    const int tid  = threadIdx.x;
    const int lane = tid & 63;
    const int wave = tid >> 6;
    const int wr = wave & 1;             // 0..1 (M)
    const int wc = wave >> 1;            // 0..3 (N)
    const long bm = (long)by * BM;
    const long bn = (long)bx * BN;
    const int  K = D_MODEL, N = D_MODEL;

    // ---- staging addressing (identical to round-2, correctness-verified) ----
    const int sp  = tid & 7;             // physical 16B chunk
    const int rA0 = tid >> 3;            // rows 0..63 (+128 for 2nd load)
    const int rA1 = 64 + rA0;            // rows 64..127 (+128)
    const int rBe = ((tid >> 8) << 6) + ((tid >> 3) & 31);   // even 32-slices
    const int rBo = rBe + 32;                                // odd 32-slices
    const __bf16* gA0 = A  + (bm + rA0) * (long)K + ((sp ^ (rA0 & 7)) << 3);
    const __bf16* gA1 = A  + (bm + rA1) * (long)K + ((sp ^ (rA1 & 7)) << 3);
    const __bf16* gBe = Bm + (bn + rBe) * (long)K + ((sp ^ (rBe & 7)) << 3);
    const __bf16* gBo = Bm + (bn + rBo) * (long)K + ((sp ^ (rBo & 7)) << 3);
    const long l128K = 128L * K;         // second load = +128 rows, LDS +16384B
    const int lA0 = tid * 16;
    const int lA1 = 8192 + tid * 16;
    const int lBe = B_OFF + ((tid >> 8) << 13) + (((tid >> 3) & 31) << 7) + sp * 16;
    const int lBo = lBe + 4096;

    auto issue2 = [&](const __bf16* g, int ldsByte) {
        async_load16(g, lds + ldsByte);
        async_load16(g + l128K, lds + ldsByte + 16384);
    };

    // prologue: stage tile 0 fully (8 loads), drain, barrier
    issue2(gA0, lA0); gA0 += BK;
    issue2(gBe, lBe); gBe += BK;
    issue2(gBo, lBo); gBo += BK;
    issue2(gA1, lA1); gA1 += BK;
    __builtin_amdgcn_sched_barrier(0);
    VMCNT(0);
    wg_barrier();

    // ---- fragment read addressing ----
    const int lm   = lane & 15;
    const int ksel = lane >> 4;          // 0..3
    const int m3   = lm & 7;
    const int clo  = ksel ^ (m3 & 3);
    const int cb0  = ((((m3 >> 2) << 2) | clo) << 4);        // phys chunk byte, s=0
    const int cb1  = ((((1 ^ (m3 >> 2)) << 2) | clo) << 4);  // phys chunk byte, s=1
    const int aBase = (wr * 128 + lm) * 128;                 // A row-major, 128 B/row
    const int bBase = B_OFF + (wc * 64 + lm) * 128;

    f32x4 acc[8][4] = {};

    int cur = 0;
#pragma unroll 1
    for (int t = 0; t < NT; ++t) {
        const char* bufc = lds + cur;
        const int stg = cur ^ BUF_BYTES;
        // stage tile t+1 into the idle buffer (last read at tile t-1's barrier)
        if (t + 1 < NT) {
            issue2(gA0, lA0 + stg); gA0 += BK;
            issue2(gBe, lBe + stg); gBe += BK;
            issue2(gBo, lBo + stg); gBo += BK;
            issue2(gA1, lA1 + stg); gA1 += BK;
        }
        // ---- software-pipelined K-tile: reads hidden under the MFMA stream ----
        bf16x8 bfr0[4], bfr1[4], afr[8];
#pragma unroll
        for (int j = 0; j < 4; ++j)
            bfr0[j] = *(const bf16x8*)(bufc + bBase + j * 2048 + cb0);
#pragma unroll
        for (int i = 0; i < 8; ++i)
            afr[i] = *(const bf16x8*)(bufc + aBase + i * 2048 + cb0);
#pragma unroll
        for (int j = 0; j < 4; ++j)
            bfr1[j] = *(const bf16x8*)(bufc + bBase + j * 2048 + cb1);
        __builtin_amdgcn_s_setprio(1);
#pragma unroll
        for (int i = 0; i < 8; ++i) {
#pragma unroll
            for (int j = 0; j < 4; ++j)
                acc[i][j] = __builtin_amdgcn_mfma_f32_16x16x32_bf16(
                    afr[i], bfr0[j], acc[i][j], 0, 0, 0);
            // slice-1 A re-read into the same slot: WAR pins it right after
            // its consumers; issues under the remaining slice-0 MFMAs
            afr[i] = *(const bf16x8*)(bufc + aBase + i * 2048 + cb1);
        }
#pragma unroll
        for (int i = 0; i < 8; ++i)
#pragma unroll
            for (int j = 0; j < 4; ++j)
                acc[i][j] = __builtin_amdgcn_mfma_f32_16x16x32_bf16(
                    afr[i], bfr1[j], acc[i][j], 0, 0, 0);
        __builtin_amdgcn_s_setprio(0);
        // single end-of-tile sync: loads for t+1 issued a full K-tile ago
        __builtin_amdgcn_sched_barrier(0);
        if (t + 1 < NT) VMCNT(0);
        wg_barrier();
        cur ^= BUF_BYTES;
    }

    // epilogue: C elem (row = (lane>>4)*4 + r, col = lane&15)
    const int r0m = (lane >> 4) << 2;
#pragma unroll
    for (int i = 0; i < 8; ++i) {
        const long mg = bm + wr * 128 + i * 16 + r0m;
#pragma unroll
        for (int j = 0; j < 4; ++j) {
            const long ng = bn + wc * 64 + j * 16 + lm;
            const float bia = bias[ng];
#pragma unroll
            for (int r = 0; r < 4; ++r) {
                float v = acc[i][j][r] + bia;
                if (PHI) v = (v > 0.f) ? (v + 1.f) : __expf(v);
                C[(mg + r) * (long)N + ng] = (OUT_T)v;
            }
        }
    }
}

__global__ __launch_bounds__(512, 2) void k_gemm_qkv(
    const __bf16* __restrict__ xb,
    const __bf16* __restrict__ wq, const __bf16* __restrict__ wk, const __bf16* __restrict__ wv,
    const float* __restrict__ bq, const float* __restrict__ bk, const float* __restrict__ bv,
    __bf16* __restrict__ oq, __bf16* __restrict__ ok, __bf16* __restrict__ ov) {
    // XCD-aware bijective swizzle: 512 blocks/slice, 512 % 8 == 0
    const int flat = blockIdx.y * 8 + blockIdx.x;
    const int swz  = (flat & 7) * 64 + (flat >> 3);
    const int bx = swz & 7, by = swz >> 3;
    const int z = blockIdx.z;
    const __bf16* W = (z == 0) ? wq : (z == 1) ? wk : wv;
    const float*  b = (z == 0) ? bq : (z == 1) ? bk : bv;
    __bf16*       o = (z == 0) ? oq : (z == 1) ? ok : ov;
    if (z < 2)
        gemm256<1, __bf16>(xb, W, b, o, bx, by);   // phi(q), phi(k)
    else
        gemm256<0, __bf16>(xb, W, b, o, bx, by);   // v
}

__global__ __launch_bounds__(512, 2) void k_gemm_out(
    const __bf16* __restrict__ ctx, const __bf16* __restrict__ wo,
    const float* __restrict__ bo, float* __restrict__ out) {
    const int flat = blockIdx.y * 8 + blockIdx.x;
    const int swz  = (flat & 7) * 64 + (flat >> 3);
    gemm256<0, float>(ctx, wo, bo, out, swz & 7, swz >> 3);
}

// ---------------- scan pass 1: per-segment sums of phi_k * v ----------------
__global__ __launch_bounds__(256) void k_scan_partial(
    const __bf16* __restrict__ phik, const __bf16* __restrict__ v,
    float* __restrict__ partial) {
    const int b  = blockIdx.z;
    const int s  = blockIdx.y;
    const int c0 = blockIdx.x * 1024 + threadIdx.x * 4;
    long base = ((long)b * SEQ + (long)s * SEGLEN) * D_MODEL + c0;
    const bf16x4* pk = (const bf16x4*)(phik + base);
    const bf16x4* pv = (const bf16x4*)(v + base);
    float s0 = 0, s1 = 0, s2 = 0, s3 = 0;
    for (int l = 0; l < SEGLEN; l++) {
        bf16x4 a = *pk, w = *pv;
        s0 += (float)a[0] * (float)w[0];
        s1 += (float)a[1] * (float)w[1];
        s2 += (float)a[2] * (float)w[2];
        s3 += (float)a[3] * (float)w[3];
        pk += D_MODEL / 4; pv += D_MODEL / 4;
    }
    *(float4*)(partial + ((long)(b * NSEG + s)) * D_MODEL + c0) = make_float4(s0, s1, s2, s3);
}

// ---------------- scan pass 2: running sum + context write (in-place over phik) ----------------
__global__ __launch_bounds__(256) void k_scan_apply(
    const __bf16* __restrict__ phiq,
    __bf16* phik_ctx,
    const __bf16* __restrict__ v,
    const float* __restrict__ partial) {
    const int b  = blockIdx.z;
    const int s  = blockIdx.y;
    const int c0 = blockIdx.x * 1024 + threadIdx.x * 4;
    float r0 = 0, r1 = 0, r2 = 0, r3 = 0;
    for (int sp = 0; sp < s; sp++) {
        float4 p = *(const float4*)(partial + ((long)(b * NSEG + sp)) * D_MODEL + c0);
        r0 += p.x; r1 += p.y; r2 += p.z; r3 += p.w;
    }
    long base = ((long)b * SEQ + (long)s * SEGLEN) * D_MODEL + c0;
    bf16x4* pk = (bf16x4*)(phik_ctx + base);
    const bf16x4* pv = (const bf16x4*)(v + base);
    const bf16x4* pq = (const bf16x4*)(phiq + base);
    for (int l = 0; l < SEGLEN; l++) {
        bf16x4 a = *pk, w = *pv, q = *pq;
        r0 += (float)a[0] * (float)w[0];
        r1 += (float)a[1] * (float)w[1];
        r2 += (float)a[2] * (float)w[2];
        r3 += (float)a[3] * (float)w[3];
        bf16x4 o;
        o[0] = (__bf16)((float)q[0] * r0 * ATTN_SCALE);
        o[1] = (__bf16)((float)q[1] * r1 * ATTN_SCALE);
        o[2] = (__bf16)((float)q[2] * r2 * ATTN_SCALE);
        o[3] = (__bf16)((float)q[3] * r3 * ATTN_SCALE);
        *pk = o;
        pk += D_MODEL / 4; pv += D_MODEL / 4; pq += D_MODEL / 4;
    }
}

// ---------------- launch ----------------
extern "C" void kernel_launch(void* const* d_in, const int* in_sizes, int n_in,
                              void* d_out, int out_size, void* d_ws, size_t ws_size,
                              hipStream_t stream) {
    const float* x  = (const float*)d_in[0];
    const float* Wq = (const float*)d_in[1];
    const float* bq = (const float*)d_in[2];
    const float* Wk = (const float*)d_in[3];
    const float* bk = (const float*)d_in[4];
    const float* Wv = (const float*)d_in[5];
    const float* bv = (const float*)d_in[6];
    const float* Wo = (const float*)d_in[7];
    const float* bo = (const float*)d_in[8];

    const size_t XB = (size_t)M_TOK * D_MODEL;
    const size_t WB = (size_t)D_MODEL * D_MODEL;

    char* p = (char*)d_ws;
    __bf16* xb   = (__bf16*)p; p += XB * 2;
    __bf16* wqb  = (__bf16*)p; p += WB * 2;   // wq,wk,wv,wo contiguous
    __bf16* wkb  = (__bf16*)p; p += WB * 2;
    __bf16* wvb  = (__bf16*)p; p += WB * 2;
    __bf16* wob  = (__bf16*)p; p += WB * 2;
    __bf16* phiq = (__bf16*)p; p += XB * 2;
    __bf16* phik = (__bf16*)p; p += XB * 2;
    __bf16* vb   = (__bf16*)p; p += XB * 2;
    if ((size_t)(p - (char*)d_ws) > ws_size) return;

    float*  partial = (float*)xb;  // xb dead after QKV GEMMs
    __bf16* ctx     = phik;        // context in-place over phi_k

    // one-time: allow 128 KiB dynamic LDS on the GEMM kernels (host-side, capture-safe)
    static bool attr_done = false;
    if (!attr_done) {
        hipFuncSetAttribute(reinterpret_cast<const void*>(&k_gemm_qkv),
                            hipFuncAttributeMaxDynamicSharedMemorySize, 131072);
        hipFuncSetAttribute(reinterpret_cast<const void*>(&k_gemm_out),
                            hipFuncAttributeMaxDynamicSharedMemorySize, 131072);
        attr_done = true;
    }

    // 1) casts
    k_cast_bf16<<<dim3((unsigned)(XB / 8 / 256)), 256, 0, stream>>>(x, xb, (int)(XB / 8));
    k_cast_w4<<<dim3((unsigned)(WB / 8 / 256), 4), 256, 0, stream>>>(Wq, Wk, Wv, Wo, wqb, (int)(WB / 8));

    // 2) fused QKV projection (+phi on q,k) — 256x256 pipelined GEMM
    k_gemm_qkv<<<dim3(D_MODEL / BN, M_TOK / BM, 3), 512, 131072, stream>>>(
        xb, wqb, wkb, wvb, bq, bk, bv, phiq, phik, vb);

    // 3) segmented prefix sum of phi_k * v, then context = phi_q * cumsum * scale
    k_scan_partial<<<dim3(2, NSEG, BATCH), 256, 0, stream>>>(phik, vb, partial);
    k_scan_apply<<<dim3(2, NSEG, BATCH), 256, 0, stream>>>(phiq, phik, vb, partial);

    // 4) output projection -> fp32 d_out
    k_gemm_out<<<dim3(D_MODEL / BN, M_TOK / BM, 1), 512, 131072, stream>>>(
        ctx, wob, bo, (float*)d_out);
}

// Round 11
// 799.091 us; speedup vs baseline: 1.0078x; 1.0078x over previous
//
#include <hip/hip_runtime.h>
#include <hip/hip_bf16.h>
#include <cstdint>
#include <cstddef>

// ---------------- types ----------------
typedef __bf16 bf16x8 __attribute__((ext_vector_type(8)));
typedef __bf16 bf16x4 __attribute__((ext_vector_type(4)));
typedef float  f32x4  __attribute__((ext_vector_type(4)));

#define D_MODEL 2048
#define SEQ     4096
#define BATCH   4
#define M_TOK   (BATCH * SEQ)            // 16384 tokens
#define ATTN_SCALE 0.08838834764831845f  // 128^-0.5

// ---- 256x256 GEMM geometry ----
#define BM 256
#define BN 256
#define BK 64
#define NT (D_MODEL / BK)                // 32 K-tiles
#define BUF_BYTES 65536                  // per buffer: A 32KB + B 32KB
#define B_OFF     32768                  // B region offset within buffer

#define NSEG   64
#define SEGLEN (SEQ / NSEG)              // 64

// ---------------- helpers ----------------
__device__ __forceinline__ void async_load16(const void* g, void* l) {
    __builtin_amdgcn_global_load_lds(
        (const __attribute__((address_space(1))) unsigned int*)g,
        (__attribute__((address_space(3))) unsigned int*)l,
        16, 0, 0);
}

__device__ __forceinline__ void wg_barrier() {
    __builtin_amdgcn_sched_barrier(0);
    __builtin_amdgcn_s_barrier();
    __builtin_amdgcn_sched_barrier(0);
}

#define VMCNT(n) asm volatile("s_waitcnt vmcnt(" #n ")" ::: "memory")

// ---------------- cast fp32 -> bf16 (8 elems / thread) ----------------
__global__ __launch_bounds__(256) void k_cast_bf16(const float* __restrict__ in,
                                                   __bf16* __restrict__ out,
                                                   int n8) {
    int i = blockIdx.x * 256 + threadIdx.x;
    if (i >= n8) return;
    const float4* in4 = (const float4*)in;
    float4 a = in4[2 * i];
    float4 b = in4[2 * i + 1];
    bf16x8 o;
    o[0] = (__bf16)a.x; o[1] = (__bf16)a.y; o[2] = (__bf16)a.z; o[3] = (__bf16)a.w;
    o[4] = (__bf16)b.x; o[5] = (__bf16)b.y; o[6] = (__bf16)b.z; o[7] = (__bf16)b.w;
    ((bf16x8*)out)[i] = o;
}

__global__ __launch_bounds__(256) void k_cast_w4(const float* __restrict__ w0,
                                                 const float* __restrict__ w1,
                                                 const float* __restrict__ w2,
                                                 const float* __restrict__ w3,
                                                 __bf16* __restrict__ out, int n8) {
    const float* srcs[4] = {w0, w1, w2, w3};
    const float* in = srcs[blockIdx.y];
    __bf16* o = out + (size_t)blockIdx.y * (size_t)n8 * 8;
    int i = blockIdx.x * 256 + threadIdx.x;
    if (i >= n8) return;
    const float4* in4 = (const float4*)in;
    float4 a = in4[2 * i];
    float4 b = in4[2 * i + 1];
    bf16x8 v;
    v[0] = (__bf16)a.x; v[1] = (__bf16)a.y; v[2] = (__bf16)a.z; v[3] = (__bf16)a.w;
    v[4] = (__bf16)b.x; v[5] = (__bf16)b.y; v[6] = (__bf16)b.z; v[7] = (__bf16)b.w;
    ((bf16x8*)o)[i] = v;
}

// ---------------- 256x256 GEMM: C = A (MxK) * B^T (B is NxK) ----------------
// 512 threads = 8 waves (2M x 4N), wave tile 128x64, MFMA 16x16x32 bf16.
// LDS: 2 buffers x (A[256][64] + B[256][64]) bf16 = 128 KiB, double buffered.
// Swizzle: 16B chunk c of row r at physical chunk c^(r&7); applied on the GLOBAL
// source of global_load_lds (LDS dest lane-linear) and on the ds_read side.
//
// Round-9 PMC: MfmaUtil 52%, cyc/K-tile 4541 = MFMA(2484) + LDS-read(2304)
// still SERIAL at CU level: barrier-synced waves are all in the same
// read/MFMA phase, so LDS pipe and matrix pipes alternate instead of
// overlapping. Fix: ANTI-PHASE SLICE STAGGER — both k-slices are valid in
// LDS between tile barriers, so half the waves consume slice 0 then 1, the
// other half 1 then 0. SIMD partners in opposite groups -> one wave reads
// while the other MFMAs -> both pipes busy. Group = (wave ^ (wave>>2)) & 1
// anti-phases partners under both plausible wave->SIMD mappings
// (i%4: pairs {i,i+4}; i/2: pairs {2k,2k+1}).
template <int PHI, typename OUT_T>
__device__ __forceinline__ void gemm256(const __bf16* __restrict__ A,
                                        const __bf16* __restrict__ Bm,
                                        const float* __restrict__ bias,
                                        OUT_T* __restrict__ C,
                                        int bx, int by) {
    extern __shared__ bf16x8 lds_dyn[];
    char* lds = (char*)lds_dyn;

    const int tid  = threadIdx.x;
    const int lane = tid & 63;
    const int wave = tid >> 6;
    const int wr = wave & 1;             // 0..1 (M)
    const int wc = wave >> 1;            // 0..3 (N)
    const int sgrp = (wave ^ (wave >> 2)) & 1;   // slice-order group
    const long bm = (long)by * BM;
    const long bn = (long)bx * BN;
    const int  K = D_MODEL, N = D_MODEL;

    // ---- staging addressing (identical to round-2, correctness-verified) ----
    const int sp  = tid & 7;             // physical 16B chunk
    const int rA0 = tid >> 3;            // rows 0..63 (+128 for 2nd load)
    const int rA1 = 64 + rA0;            // rows 64..127 (+128)
    const int rBe = ((tid >> 8) << 6) + ((tid >> 3) & 31);   // even 32-slices
    const int rBo = rBe + 32;                                // odd 32-slices
    const __bf16* gA0 = A  + (bm + rA0) * (long)K + ((sp ^ (rA0 & 7)) << 3);
    const __bf16* gA1 = A  + (bm + rA1) * (long)K + ((sp ^ (rA1 & 7)) << 3);
    const __bf16* gBe = Bm + (bn + rBe) * (long)K + ((sp ^ (rBe & 7)) << 3);
    const __bf16* gBo = Bm + (bn + rBo) * (long)K + ((sp ^ (rBo & 7)) << 3);
    const long l128K = 128L * K;         // second load = +128 rows, LDS +16384B
    const int lA0 = tid * 16;
    const int lA1 = 8192 + tid * 16;
    const int lBe = B_OFF + ((tid >> 8) << 13) + (((tid >> 3) & 31) << 7) + sp * 16;
    const int lBo = lBe + 4096;

    auto issue2 = [&](const __bf16* g, int ldsByte) {
        async_load16(g, lds + ldsByte);
        async_load16(g + l128K, lds + ldsByte + 16384);
    };

    // prologue: stage tile 0 fully (8 loads), drain, barrier
    issue2(gA0, lA0); gA0 += BK;
    issue2(gBe, lBe); gBe += BK;
    issue2(gBo, lBo); gBo += BK;
    issue2(gA1, lA1); gA1 += BK;
    __builtin_amdgcn_sched_barrier(0);
    VMCNT(0);
    wg_barrier();

    // ---- fragment read addressing ----
    const int lm   = lane & 15;
    const int ksel = lane >> 4;          // 0..3
    const int m3   = lm & 7;
    const int clo  = ksel ^ (m3 & 3);
    const int cb0  = ((((m3 >> 2) << 2) | clo) << 4);        // phys chunk byte, s=0
    const int cb1  = ((((1 ^ (m3 >> 2)) << 2) | clo) << 4);  // phys chunk byte, s=1
    const int aBase = (wr * 128 + lm) * 128;                 // A row-major, 128 B/row
    const int bBase = B_OFF + (wc * 64 + lm) * 128;

    f32x4 acc[8][4] = {};

    int cur = 0;
#pragma unroll 1
    for (int t = 0; t < NT; ++t) {
        const char* bufc = lds + cur;
        const int stg = cur ^ BUF_BYTES;
        // stage tile t+1 into the idle buffer (last read at tile t-1's barrier)
        if (t + 1 < NT) {
            issue2(gA0, lA0 + stg); gA0 += BK;
            issue2(gBe, lBe + stg); gBe += BK;
            issue2(gBo, lBo + stg); gBo += BK;
            issue2(gA1, lA1 + stg); gA1 += BK;
        }
        // ---- anti-phase k-slices: group 0 does s=0,1; group 1 does s=1,0 ----
#pragma unroll
        for (int ss = 0; ss < 2; ++ss) {
            const int cbs = (ss ^ sgrp) ? cb1 : cb0;
            bf16x8 afr[8], bfr[4];
#pragma unroll
            for (int j = 0; j < 4; ++j)
                bfr[j] = *(const bf16x8*)(bufc + bBase + j * 2048 + cbs);
#pragma unroll
            for (int i = 0; i < 8; ++i)
                afr[i] = *(const bf16x8*)(bufc + aBase + i * 2048 + cbs);
            __builtin_amdgcn_s_setprio(1);
#pragma unroll
            for (int i = 0; i < 8; ++i)
#pragma unroll
                for (int j = 0; j < 4; ++j)
                    acc[i][j] = __builtin_amdgcn_mfma_f32_16x16x32_bf16(
                        afr[i], bfr[j], acc[i][j], 0, 0, 0);
            __builtin_amdgcn_s_setprio(0);
        }
        // single end-of-tile sync: loads for t+1 issued a full K-tile ago
        __builtin_amdgcn_sched_barrier(0);
        if (t + 1 < NT) VMCNT(0);
        wg_barrier();
        cur ^= BUF_BYTES;
    }

    // epilogue: C elem (row = (lane>>4)*4 + r, col = lane&15)
    const int r0m = (lane >> 4) << 2;
#pragma unroll
    for (int i = 0; i < 8; ++i) {
        const long mg = bm + wr * 128 + i * 16 + r0m;
#pragma unroll
        for (int j = 0; j < 4; ++j) {
            const long ng = bn + wc * 64 + j * 16 + lm;
            const float bia = bias[ng];
#pragma unroll
            for (int r = 0; r < 4; ++r) {
                float v = acc[i][j][r] + bia;
                if (PHI) v = (v > 0.f) ? (v + 1.f) : __expf(v);
                C[(mg + r) * (long)N + ng] = (OUT_T)v;
            }
        }
    }
}

__global__ __launch_bounds__(512, 2) void k_gemm_qkv(
    const __bf16* __restrict__ xb,
    const __bf16* __restrict__ wq, const __bf16* __restrict__ wk, const __bf16* __restrict__ wv,
    const float* __restrict__ bq, const float* __restrict__ bk, const float* __restrict__ bv,
    __bf16* __restrict__ oq, __bf16* __restrict__ ok, __bf16* __restrict__ ov) {
    // XCD-aware bijective swizzle: 512 blocks/slice, 512 % 8 == 0
    const int flat = blockIdx.y * 8 + blockIdx.x;
    const int swz  = (flat & 7) * 64 + (flat >> 3);
    const int bx = swz & 7, by = swz >> 3;
    const int z = blockIdx.z;
    const __bf16* W = (z == 0) ? wq : (z == 1) ? wk : wv;
    const float*  b = (z == 0) ? bq : (z == 1) ? bk : bv;
    __bf16*       o = (z == 0) ? oq : (z == 1) ? ok : ov;
    if (z < 2)
        gemm256<1, __bf16>(xb, W, b, o, bx, by);   // phi(q), phi(k)
    else
        gemm256<0, __bf16>(xb, W, b, o, bx, by);   // v
}

__global__ __launch_bounds__(512, 2) void k_gemm_out(
    const __bf16* __restrict__ ctx, const __bf16* __restrict__ wo,
    const float* __restrict__ bo, float* __restrict__ out) {
    const int flat = blockIdx.y * 8 + blockIdx.x;
    const int swz  = (flat & 7) * 64 + (flat >> 3);
    gemm256<0, float>(ctx, wo, bo, out, swz & 7, swz >> 3);
}

// ---------------- scan pass 1: per-segment sums of phi_k * v ----------------
__global__ __launch_bounds__(256) void k_scan_partial(
    const __bf16* __restrict__ phik, const __bf16* __restrict__ v,
    float* __restrict__ partial) {
    const int b  = blockIdx.z;
    const int s  = blockIdx.y;
    const int c0 = blockIdx.x * 1024 + threadIdx.x * 4;
    long base = ((long)b * SEQ + (long)s * SEGLEN) * D_MODEL + c0;
    const bf16x4* pk = (const bf16x4*)(phik + base);
    const bf16x4* pv = (const bf16x4*)(v + base);
    float s0 = 0, s1 = 0, s2 = 0, s3 = 0;
    for (int l = 0; l < SEGLEN; l++) {
        bf16x4 a = *pk, w = *pv;
        s0 += (float)a[0] * (float)w[0];
        s1 += (float)a[1] * (float)w[1];
        s2 += (float)a[2] * (float)w[2];
        s3 += (float)a[3] * (float)w[3];
        pk += D_MODEL / 4; pv += D_MODEL / 4;
    }
    *(float4*)(partial + ((long)(b * NSEG + s)) * D_MODEL + c0) = make_float4(s0, s1, s2, s3);
}

// ---------------- scan pass 2: running sum + context write (in-place over phik) ----------------
__global__ __launch_bounds__(256) void k_scan_apply(
    const __bf16* __restrict__ phiq,
    __bf16* phik_ctx,
    const __bf16* __restrict__ v,
    const float* __restrict__ partial) {
    const int b  = blockIdx.z;
    const int s  = blockIdx.y;
    const int c0 = blockIdx.x * 1024 + threadIdx.x * 4;
    float r0 = 0, r1 = 0, r2 = 0, r3 = 0;
    for (int sp = 0; sp < s; sp++) {
        float4 p = *(const float4*)(partial + ((long)(b * NSEG + sp)) * D_MODEL + c0);
        r0 += p.x; r1 += p.y; r2 += p.z; r3 += p.w;
    }
    long base = ((long)b * SEQ + (long)s * SEGLEN) * D_MODEL + c0;
    bf16x4* pk = (bf16x4*)(phik_ctx + base);
    const bf16x4* pv = (const bf16x4*)(v + base);
    const bf16x4* pq = (const bf16x4*)(phiq + base);
    for (int l = 0; l < SEGLEN; l++) {
        bf16x4 a = *pk, w = *pv, q = *pq;
        r0 += (float)a[0] * (float)w[0];
        r1 += (float)a[1] * (float)w[1];
        r2 += (float)a[2] * (float)w[2];
        r3 += (float)a[3] * (float)w[3];
        bf16x4 o;
        o[0] = (__bf16)((float)q[0] * r0 * ATTN_SCALE);
        o[1] = (__bf16)((float)q[1] * r1 * ATTN_SCALE);
        o[2] = (__bf16)((float)q[2] * r2 * ATTN_SCALE);
        o[3] = (__bf16)((float)q[3] * r3 * ATTN_SCALE);
        *pk = o;
        pk += D_MODEL / 4; pv += D_MODEL / 4; pq += D_MODEL / 4;
    }
}

// ---------------- launch ----------------
extern "C" void kernel_launch(void* const* d_in, const int* in_sizes, int n_in,
                              void* d_out, int out_size, void* d_ws, size_t ws_size,
                              hipStream_t stream) {
    const float* x  = (const float*)d_in[0];
    const float* Wq = (const float*)d_in[1];
    const float* bq = (const float*)d_in[2];
    const float* Wk = (const float*)d_in[3];
    const float* bk = (const float*)d_in[4];
    const float* Wv = (const float*)d_in[5];
    const float* bv = (const float*)d_in[6];
    const float* Wo = (const float*)d_in[7];
    const float* bo = (const float*)d_in[8];

    const size_t XB = (size_t)M_TOK * D_MODEL;
    const size_t WB = (size_t)D_MODEL * D_MODEL;

    char* p = (char*)d_ws;
    __bf16* xb   = (__bf16*)p; p += XB * 2;
    __bf16* wqb  = (__bf16*)p; p += WB * 2;   // wq,wk,wv,wo contiguous
    __bf16* wkb  = (__bf16*)p; p += WB * 2;
    __bf16* wvb  = (__bf16*)p; p += WB * 2;
    __bf16* wob  = (__bf16*)p; p += WB * 2;
    __bf16* phiq = (__bf16*)p; p += XB * 2;
    __bf16* phik = (__bf16*)p; p += XB * 2;
    __bf16* vb   = (__bf16*)p; p += XB * 2;
    if ((size_t)(p - (char*)d_ws) > ws_size) return;

    float*  partial = (float*)xb;  // xb dead after QKV GEMMs
    __bf16* ctx     = phik;        // context in-place over phi_k

    // one-time: allow 128 KiB dynamic LDS on the GEMM kernels (host-side, capture-safe)
    static bool attr_done = false;
    if (!attr_done) {
        hipFuncSetAttribute(reinterpret_cast<const void*>(&k_gemm_qkv),
                            hipFuncAttributeMaxDynamicSharedMemorySize, 131072);
        hipFuncSetAttribute(reinterpret_cast<const void*>(&k_gemm_out),
                            hipFuncAttributeMaxDynamicSharedMemorySize, 131072);
        attr_done = true;
    }

    // 1) casts
    k_cast_bf16<<<dim3((unsigned)(XB / 8 / 256)), 256, 0, stream>>>(x, xb, (int)(XB / 8));
    k_cast_w4<<<dim3((unsigned)(WB / 8 / 256), 4), 256, 0, stream>>>(Wq, Wk, Wv, Wo, wqb, (int)(WB / 8));

    // 2) fused QKV projection (+phi on q,k) — 256x256 anti-phase GEMM
    k_gemm_qkv<<<dim3(D_MODEL / BN, M_TOK / BM, 3), 512, 131072, stream>>>(
        xb, wqb, wkb, wvb, bq, bk, bv, phiq, phik, vb);

    // 3) segmented prefix sum of phi_k * v, then context = phi_q * cumsum * scale
    k_scan_partial<<<dim3(2, NSEG, BATCH), 256, 0, stream>>>(phik, vb, partial);
    k_scan_apply<<<dim3(2, NSEG, BATCH), 256, 0, stream>>>(phiq, phik, vb, partial);

    // 4) output projection -> fp32 d_out
    k_gemm_out<<<dim3(D_MODEL / BN, M_TOK / BM, 1), 512, 131072, stream>>>(
        ctx, wob, bo, (float*)d_out);
}